// Round 11
// baseline (222.278 us; speedup 1.0000x reference)
//
#include <hip/hip_runtime.h>
#include <cmath>

#define NPTS 1048576
#define TABLE_SZ 524288
#define NBUCK 32768   // 32^3 spatial buckets

typedef _Float16 half8 __attribute__((ext_vector_type(8)));
typedef _Float16 half4 __attribute__((ext_vector_type(4)));
typedef _Float16 h2 __attribute__((ext_vector_type(2)));
typedef __fp16 fp16x2 __attribute__((ext_vector_type(2)));
typedef float floatx4 __attribute__((ext_vector_type(4)));
typedef unsigned int uint2a4 __attribute__((ext_vector_type(2), aligned(4)));

#define MFMA16x16x32 __builtin_amdgcn_mfma_f32_16x16x32_f16

__device__ __forceinline__ h2 as_h2(unsigned int u) {
    union { unsigned int u; h2 h; } c; c.u = u; return c.h;
}
__device__ __forceinline__ unsigned int pk_u32(float a, float b) {
    union { fp16x2 h; unsigned int u; } c;
    c.h = __builtin_amdgcn_cvt_pkrtz(a, b);
    return c.u;
}

// ---------------------------------------------------------------------------
// Pre-pack all MLP weights into f16 MFMA A-fragments (W^T as A operand).
// wc0 stored SHIFTED: row16 = 0, rows 17..31 = wc0 rows 16..30.
// ---------------------------------------------------------------------------
__global__ void prepack_weights(const float* __restrict__ ws0,
                                const float* __restrict__ ws1,
                                const float* __restrict__ wc0,
                                const float* __restrict__ wc1,
                                const float* __restrict__ wc2,
                                half8* __restrict__ wfrag)
{
    const int f = blockIdx.x, l = threadIdx.x;
    const int lane_m = l & 15, k0 = (l >> 4) * 8;
    half8 hv;

    if (f >= 6 && f < 10) {               // wc0' (shifted), M=64, K=32
        const int m = 16*(f-6) + lane_m;
        #pragma unroll
        for (int e = 0; e < 8; ++e) {
            const int k = k0 + e;
            float v;
            if (k < 16)       v = wc0[k*64 + m];
            else if (k == 16) v = 0.0f;
            else              v = wc0[(k-1)*64 + m];
            hv[e] = (_Float16)v;
        }
        wfrag[f*64 + l] = hv;
        return;
    }

    const float* W; int Kreal, Mreal, mt, kt;
    if (f < 4)       { W = ws0; Kreal = 32; Mreal = 64; mt = f;          kt = 0;        }
    else if (f < 6)  { W = ws1; Kreal = 64; Mreal = 16; mt = 0;          kt = f - 4;    }
    else if (f < 18) { W = wc1; Kreal = 64; Mreal = 64; mt = (f-10)>>1;  kt = (f-10)&1; }
    else             { W = wc2; Kreal = 64; Mreal = 1;  mt = 0;          kt = f - 18;   }

    const int m  = 16*mt + lane_m;
    const int kk0 = 32*kt + k0;
    #pragma unroll
    for (int e = 0; e < 8; ++e) {
        const int k = kk0 + e;
        const float v = (m < Mreal && k < Kreal) ? W[k*Mreal + m] : 0.0f;
        hv[e] = (_Float16)v;
    }
    wfrag[f*64 + l] = hv;
}

// ---------------------------------------------------------------------------
// Convert ACTIVE region of each level's fp32 table to packed f16.
// blockIdx.y==16 zeroes the histogram.
// ---------------------------------------------------------------------------
__global__ __launch_bounds__(256) void convert_tables(
    const float* __restrict__ emb, unsigned int* __restrict__ tabu,
    unsigned int* __restrict__ hist, int zero_hist,
    int4 ra, int4 rb, int4 rc, int4 rd,
    int4 oa, int4 ob, int4 oc, int4 od)
{
    const int l = blockIdx.y;
    if (l == 16) {
        if (zero_hist) {
            const int e = blockIdx.x * 256 + threadIdx.x;
            if (e < NBUCK) hist[e] = 0u;
        }
        return;
    }
    const int q = l >> 2, j = l & 3;
    const int4 rv = (q == 0) ? ra : (q == 1) ? rb : (q == 2) ? rc : rd;
    const int4 ov = (q == 0) ? oa : (q == 1) ? ob : (q == 2) ? oc : od;
    const int R   = (j == 0) ? rv.x : (j == 1) ? rv.y : (j == 2) ? rv.z : rv.w;
    const int off = (j == 0) ? ov.x : (j == 1) ? ov.y : (j == 2) ? ov.z : ov.w;
    const int n = (R+1)*(R+1)*(R+1);
    const int e = blockIdx.x * 256 + threadIdx.x;
    if (e >= n) return;
    const float2 v = *(const float2*)(emb + (size_t)l * (TABLE_SZ*2) + 2*(size_t)e);
    tabu[off + e] = pk_u32(v.x, v.y);
}

// ---------------------------------------------------------------------------
// Spatial counting sort (32^3 buckets), inverted-permutation variant:
// scattered STORES are minimized (4B inv), heavy data moves via scattered
// READS (L2/L3-shared) + coalesced stores.
// ---------------------------------------------------------------------------
__device__ __forceinline__ int bucket_of(float px, float py, float pz) {
    int bx = (int)(px * 32.0f); bx = bx < 0 ? 0 : (bx > 31 ? 31 : bx);
    int by = (int)(py * 32.0f); by = by < 0 ? 0 : (by > 31 ? 31 : by);
    int bz = (int)(pz * 32.0f); bz = bz < 0 ? 0 : (bz > 31 ? 31 : bz);
    return bx | (by << 5) | (bz << 10);
}

__global__ __launch_bounds__(256) void hist_kernel(
    const float* __restrict__ xin, unsigned int* __restrict__ hist,
    unsigned int* __restrict__ rnk)
{
    const int i = blockIdx.x * 256 + threadIdx.x;
    const float px = (xin[3*i+0] + 1.0f) * 0.5f;
    const float py = (xin[3*i+1] + 1.0f) * 0.5f;
    const float pz = (xin[3*i+2] + 1.0f) * 0.5f;
    rnk[i] = atomicAdd(&hist[bucket_of(px, py, pz)], 1u);
}

__global__ __launch_bounds__(1024) void scan_kernel(
    const unsigned int* __restrict__ hist, unsigned int* __restrict__ off)
{
    __shared__ unsigned int ssum[1024];
    const int t = threadIdx.x;
    unsigned int v[32];
    unsigned int s = 0;
    #pragma unroll
    for (int j = 0; j < 32; ++j) {
        const unsigned int h = hist[t*32 + j];
        v[j] = s; s += h;
    }
    ssum[t] = s;
    __syncthreads();
    for (int d = 1; d < 1024; d <<= 1) {
        const unsigned int add = (t >= d) ? ssum[t-d] : 0u;
        __syncthreads();
        ssum[t] += add;
        __syncthreads();
    }
    const unsigned int base = (t == 0) ? 0u : ssum[t-1];
    #pragma unroll
    for (int j = 0; j < 32; ++j) off[t*32 + j] = base + v[j];
}

// inv[pos] = i  (only 4B scattered store per point)
__global__ __launch_bounds__(256) void inv_kernel(
    const float* __restrict__ xin, const unsigned int* __restrict__ boff,
    const unsigned int* __restrict__ rnk, unsigned int* __restrict__ inv)
{
    const int i = blockIdx.x * 256 + threadIdx.x;
    const float px = (xin[3*i+0] + 1.0f) * 0.5f;
    const float py = (xin[3*i+1] + 1.0f) * 0.5f;
    const float pz = (xin[3*i+2] + 1.0f) * 0.5f;
    const int b = bucket_of(px, py, pz);
    inv[boff[b] + rnk[i]] = (unsigned int)i;
}

// thread p (sorted): scattered READS of xin/din, coalesced 32B store.
// pd[2p]   = {px,py,pz, -}     (gather input)
// pd[2p+1] = {dx,dy,dz, orig}  (mlp input)
__global__ __launch_bounds__(256) void permute_kernel(
    const float* __restrict__ xin, const float* __restrict__ din,
    const unsigned int* __restrict__ inv, float4* __restrict__ pd)
{
    const int p = blockIdx.x * 256 + threadIdx.x;
    const unsigned int i = inv[p];
    const float px = (xin[3*i+0] + 1.0f) * 0.5f;
    const float py = (xin[3*i+1] + 1.0f) * 0.5f;
    const float pz = (xin[3*i+2] + 1.0f) * 0.5f;
    const float dx = din[3*i+0], dy = din[3*i+1], dz = din[3*i+2];
    pd[2*(size_t)p]     = make_float4(px, py, pz, 0.0f);
    pd[2*(size_t)p + 1] = make_float4(dx, dy, dz, __uint_as_float(i));
}

// ---------------------------------------------------------------------------
// Gather over SORTED points, LEVEL-MAJOR (q = blockIdx.y). Feats SoA in
// SORTED order: feats[q*NPTS + p] (half8). Position from pd[2p].
// ---------------------------------------------------------------------------
__global__ __launch_bounds__(256, 4) void ngp_gather_sorted(
    const float4* __restrict__ pd, const unsigned int* __restrict__ tabu,
    _Float16* __restrict__ feats,
    int4 ra, int4 rb, int4 rc, int4 rd,
    int4 oa, int4 ob, int4 oc, int4 od)
{
    const int p = blockIdx.x * 256 + threadIdx.x;
    const int q = blockIdx.y;

    const float4 xv = pd[2*(size_t)p];
    const float px = xv.x, py = xv.y, pz = xv.z;

    const int4 rv = (q == 0) ? ra : (q == 1) ? rb : (q == 2) ? rc : rd;
    const int4 ov = (q == 0) ? oa : (q == 1) ? ob : (q == 2) ? oc : od;

    uint2a4 P[16];
    float fx[4], fy[4], fz[4];

    #pragma unroll
    for (int j = 0; j < 4; ++j) {
        const int R   = (j == 0) ? rv.x : (j == 1) ? rv.y : (j == 2) ? rv.z : rv.w;
        const int off = (j == 0) ? ov.x : (j == 1) ? ov.y : (j == 2) ? ov.z : ov.w;
        const float Rf = (float)R;
        const float gx = px*Rf, gy = py*Rf, gz = pz*Rf;
        int x0 = (int)floorf(gx); x0 = x0 < 0 ? 0 : (x0 > R-1 ? R-1 : x0);
        int y0 = (int)floorf(gy); y0 = y0 < 0 ? 0 : (y0 > R-1 ? R-1 : y0);
        int z0 = (int)floorf(gz); z0 = z0 < 0 ? 0 : (z0 > R-1 ? R-1 : z0);
        fx[j] = gx - (float)x0; fy[j] = gy - (float)y0; fz[j] = gz - (float)z0;
        const int s1 = R + 1, s2 = s1 * s1;
        const unsigned int* tab = tabu + off;
        const int b = x0 + y0*s1 + z0*s2;
        P[4*j+0] = *(const uint2a4*)(tab + b);
        P[4*j+1] = *(const uint2a4*)(tab + b + s1);
        P[4*j+2] = *(const uint2a4*)(tab + b + s2);
        P[4*j+3] = *(const uint2a4*)(tab + b + s1 + s2);
    }

    union { half8 v; h2 h[4]; } hv;
    #pragma unroll
    for (int j = 0; j < 4; ++j) {
        const _Float16 fxh = (_Float16)fx[j];
        const _Float16 fyh = (_Float16)fy[j];
        const _Float16 fzh = (_Float16)fz[j];
        const h2 fx2 = {fxh, fxh}, fy2 = {fyh, fyh}, fz2 = {fzh, fzh};
        const h2 c000 = as_h2(P[4*j+0].x), c100 = as_h2(P[4*j+0].y);
        const h2 c010 = as_h2(P[4*j+1].x), c110 = as_h2(P[4*j+1].y);
        const h2 c001 = as_h2(P[4*j+2].x), c101 = as_h2(P[4*j+2].y);
        const h2 c011 = as_h2(P[4*j+3].x), c111 = as_h2(P[4*j+3].y);
        const h2 a00 = c000 + fx2 * (c100 - c000);
        const h2 a10 = c010 + fx2 * (c110 - c010);
        const h2 a01 = c001 + fx2 * (c101 - c001);
        const h2 a11 = c011 + fx2 * (c111 - c011);
        const h2 b0  = a00 + fy2 * (a10 - a00);
        const h2 b1  = a01 + fy2 * (a11 - a01);
        hv.h[j] = b0 + fz2 * (b1 - b0);
    }
    *(half8*)&feats[((size_t)q * NPTS + p) * 8] = hv.v;
}

// ---------------------------------------------------------------------------
// Unsorted gather (tier-0 fallback, f16 tables, AoS feats in orig order).
// ---------------------------------------------------------------------------
__global__ __launch_bounds__(256, 4) void ngp_gather_lin(
    const float* __restrict__ xin, const unsigned int* __restrict__ tabu,
    _Float16* __restrict__ feats,
    int4 ra, int4 rb, int4 rc, int4 rd,
    int4 oa, int4 ob, int4 oc, int4 od)
{
    const int tid = blockIdx.x * 256 + threadIdx.x;
    const int p = tid >> 2;
    const int q = tid & 3;

    const float px = (xin[3*p+0] + 1.0f) * 0.5f;
    const float py = (xin[3*p+1] + 1.0f) * 0.5f;
    const float pz = (xin[3*p+2] + 1.0f) * 0.5f;

    const int4 rv = (q == 0) ? ra : (q == 1) ? rb : (q == 2) ? rc : rd;
    const int4 ov = (q == 0) ? oa : (q == 1) ? ob : (q == 2) ? oc : od;

    uint2a4 P[16];
    float fx[4], fy[4], fz[4];
    #pragma unroll
    for (int j = 0; j < 4; ++j) {
        const int R   = (j == 0) ? rv.x : (j == 1) ? rv.y : (j == 2) ? rv.z : rv.w;
        const int off = (j == 0) ? ov.x : (j == 1) ? ov.y : (j == 2) ? ov.z : ov.w;
        const float Rf = (float)R;
        const float gx = px*Rf, gy = py*Rf, gz = pz*Rf;
        int x0 = (int)floorf(gx); x0 = x0 < 0 ? 0 : (x0 > R-1 ? R-1 : x0);
        int y0 = (int)floorf(gy); y0 = y0 < 0 ? 0 : (y0 > R-1 ? R-1 : y0);
        int z0 = (int)floorf(gz); z0 = z0 < 0 ? 0 : (z0 > R-1 ? R-1 : z0);
        fx[j] = gx - (float)x0; fy[j] = gy - (float)y0; fz[j] = gz - (float)z0;
        const int s1 = R + 1, s2 = s1 * s1;
        const unsigned int* tab = tabu + off;
        const int b = x0 + y0*s1 + z0*s2;
        P[4*j+0] = *(const uint2a4*)(tab + b);
        P[4*j+1] = *(const uint2a4*)(tab + b + s1);
        P[4*j+2] = *(const uint2a4*)(tab + b + s2);
        P[4*j+3] = *(const uint2a4*)(tab + b + s1 + s2);
    }
    union { half8 v; h2 h[4]; } hv;
    #pragma unroll
    for (int j = 0; j < 4; ++j) {
        const _Float16 fxh = (_Float16)fx[j];
        const _Float16 fyh = (_Float16)fy[j];
        const _Float16 fzh = (_Float16)fz[j];
        const h2 fx2 = {fxh, fxh}, fy2 = {fyh, fyh}, fz2 = {fzh, fzh};
        const h2 c000 = as_h2(P[4*j+0].x), c100 = as_h2(P[4*j+0].y);
        const h2 c010 = as_h2(P[4*j+1].x), c110 = as_h2(P[4*j+1].y);
        const h2 c001 = as_h2(P[4*j+2].x), c101 = as_h2(P[4*j+2].y);
        const h2 c011 = as_h2(P[4*j+3].x), c111 = as_h2(P[4*j+3].y);
        const h2 a00 = c000 + fx2 * (c100 - c000);
        const h2 a10 = c010 + fx2 * (c110 - c010);
        const h2 a01 = c001 + fx2 * (c101 - c001);
        const h2 a11 = c011 + fx2 * (c111 - c011);
        const h2 b0  = a00 + fy2 * (a10 - a00);
        const h2 b1  = a01 + fy2 * (a11 - a01);
        hv.h[j] = b0 + fz2 * (b1 - b0);
    }
    *(half8*)&feats[(size_t)p*32 + q*8] = hv.v;
}

// ---------------------------------------------------------------------------
// MLP kernel. 4 waves/block, 64 points/wave (nt=0..3), wave-private LDS.
// MODE 2: sorted, fully-coalesced loads (pd[2p+1] carries dir+orig).
// MODE 0: unsorted AoS feats.
// Scattered OUT stores are fire-and-forget (no wave stall).
// ---------------------------------------------------------------------------
template<int MODE>
__global__ __launch_bounds__(256) void ngp_mlp(
    const float* __restrict__ din, const _Float16* __restrict__ feats,
    const float4* __restrict__ pd,
    const half8* __restrict__ wfrag, float* __restrict__ out)
{
    __shared__ __align__(16) _Float16 smM[4][64][72];  // H / c1 / c2

    const int tid  = threadIdx.x;
    const int w    = tid >> 6, lane = tid & 63;
    const int gbase = (blockIdx.x * 4 + w) * 64;

    const int n = lane & 15, g = lane >> 4;
    const floatx4 zz = {0.f, 0.f, 0.f, 0.f};

    // per-nt point data: orig index + direction (coalesced in MODE 2)
    unsigned int orig[4];
    float dX[4], dY[4], dZ[4];
    #pragma unroll
    for (int nt = 0; nt < 4; ++nt) {
        const int pt = nt*16 + n;
        if (MODE == 2) {
            const float4 dv = pd[2*(size_t)(gbase + pt) + 1];
            dX[nt] = dv.x; dY[nt] = dv.y; dZ[nt] = dv.z;
            orig[nt] = __float_as_uint(dv.w);
        } else {
            orig[nt] = gbase + pt;
            dX[nt] = din[3*orig[nt]+0]; dY[nt] = din[3*orig[nt]+1]; dZ[nt] = din[3*orig[nt]+2];
        }
    }

    auto storeQ = [&](int pt, int mt, floatx4 a) {   // relu + packed f16
        union { unsigned int u[2]; half4 v; } c;
        c.u[0] = pk_u32(fmaxf(a[0], 0.f), fmaxf(a[1], 0.f));
        c.u[1] = pk_u32(fmaxf(a[2], 0.f), fmaxf(a[3], 0.f));
        *(half4*)&smM[w][pt][16*mt + 4*g] = c.v;
    };

    // ===== S0: feats[32] @ ws0 -> H[64], relu
    {
        const half8 A0 = wfrag[0*64+lane], A1 = wfrag[1*64+lane];
        const half8 A2 = wfrag[2*64+lane], A3 = wfrag[3*64+lane];
        #pragma unroll
        for (int nt = 0; nt < 4; ++nt) {
            const int pt = nt*16 + n;
            half8 B;
            if (MODE == 2)
                B = *(const half8*)&feats[((size_t)g * NPTS + (gbase + pt)) * 8];
            else
                B = *(const half8*)&feats[(size_t)(gbase + pt)*32 + 8*g];
            floatx4 a0 = MFMA16x16x32(A0, B, zz, 0,0,0);
            floatx4 a1 = MFMA16x16x32(A1, B, zz, 0,0,0);
            floatx4 a2 = MFMA16x16x32(A2, B, zz, 0,0,0);
            floatx4 a3 = MFMA16x16x32(A3, B, zz, 0,0,0);
            storeQ(pt, 0, a0); storeQ(pt, 1, a1); storeQ(pt, 2, a2); storeQ(pt, 3, a3);
        }
    }
    asm volatile("" ::: "memory");

    // ===== S1: H[64] @ ws1 -> G[16] (linear). sigma out; geo words in regs.
    unsigned int s1a[4], s1b[4];
    {
        const half8 A0 = wfrag[4*64+lane], A1 = wfrag[5*64+lane];
        #pragma unroll
        for (int nt = 0; nt < 4; ++nt) {
            const int pt = nt*16 + n;
            const half8 B0 = *(const half8*)&smM[w][pt][ 0 + 8*g];
            const half8 B1 = *(const half8*)&smM[w][pt][32 + 8*g];
            floatx4 acc = MFMA16x16x32(A0, B0, zz, 0,0,0);
            acc = MFMA16x16x32(A1, B1, acc, 0,0,0);
            s1a[nt] = pk_u32(acc[0], acc[1]);
            s1b[nt] = pk_u32(acc[2], acc[3]);
            if (g == 0) out[orig[nt]] = fabsf(acc[0]);   // sigma
        }
    }
    asm volatile("" ::: "memory");

    // ===== C0: hd'[32] @ wc0' -> c1[64], relu
    // hd' = [SH(16) ; g0..g15]; geo B via 4 shfls from S1 words.
    {
        const half8 A0 = wfrag[6*64+lane], A1 = wfrag[7*64+lane];
        const half8 A2 = wfrag[8*64+lane], A3 = wfrag[9*64+lane];
        const int srcA = ((g & 1) << 5) + n;
        #pragma unroll
        for (int nt = 0; nt < 4; ++nt) {
            const int pt = nt*16 + n;
            const unsigned int w0 = __shfl(s1a[nt], srcA);
            const unsigned int w1 = __shfl(s1b[nt], srcA);
            const unsigned int w2 = __shfl(s1a[nt], srcA + 16);
            const unsigned int w3 = __shfl(s1b[nt], srcA + 16);
            union { half8 v; unsigned int u[4]; } B;
            if (g < 2) {
                const float x = dX[nt], y = dY[nt], z = dZ[nt];
                const float xx = x*x, yy = y*y, zzq = z*z;
                const float xy = x*y, yz = y*z, xz = x*z;
                float s[8];
                if (g == 0) {
                    s[0] = 0.28209479177387814f;
                    s[1] = -0.48860251190291987f * y;
                    s[2] =  0.48860251190291987f * z;
                    s[3] = -0.48860251190291987f * x;
                    s[4] =  1.0925484305920792f * xy;
                    s[5] = -1.0925484305920792f * yz;
                    s[6] =  0.94617469575756f * zzq - 0.31539156525252005f;
                    s[7] = -1.0925484305920792f * xz;
                } else {
                    s[0] =  0.5462742152960396f * (xx - yy);
                    s[1] =  0.5900435899266435f * y * (yy - 3.0f*xx);
                    s[2] =  2.890611442640554f * xy * z;
                    s[3] =  0.4570457994644657f * y * (1.0f - 5.0f*zzq);
                    s[4] =  0.3731763325901154f * z * (5.0f*zzq - 3.0f);
                    s[5] =  0.4570457994644657f * x * (1.0f - 5.0f*zzq);
                    s[6] =  1.445305721320277f * z * (xx - yy);
                    s[7] =  0.5900435899266435f * x * (3.0f*yy - xx);
                }
                B.u[0] = pk_u32(s[0], s[1]); B.u[1] = pk_u32(s[2], s[3]);
                B.u[2] = pk_u32(s[4], s[5]); B.u[3] = pk_u32(s[6], s[7]);
            } else {
                B.u[0] = w0; B.u[1] = w1; B.u[2] = w2; B.u[3] = w3;
            }
            floatx4 a0 = MFMA16x16x32(A0, B.v, zz, 0,0,0);
            floatx4 a1 = MFMA16x16x32(A1, B.v, zz, 0,0,0);
            floatx4 a2 = MFMA16x16x32(A2, B.v, zz, 0,0,0);
            floatx4 a3 = MFMA16x16x32(A3, B.v, zz, 0,0,0);
            storeQ(pt, 0, a0); storeQ(pt, 1, a1); storeQ(pt, 2, a2); storeQ(pt, 3, a3);
        }
    }
    asm volatile("" ::: "memory");

    // ===== C1: c1[64] @ wc1 -> c2[64], relu
    {
        const half8 A0 = wfrag[10*64+lane], A1 = wfrag[11*64+lane];
        const half8 A2 = wfrag[12*64+lane], A3 = wfrag[13*64+lane];
        const half8 A4 = wfrag[14*64+lane], A5 = wfrag[15*64+lane];
        const half8 A6 = wfrag[16*64+lane], A7 = wfrag[17*64+lane];
        #pragma unroll
        for (int nt = 0; nt < 4; ++nt) {
            const int pt = nt*16 + n;
            const half8 B0 = *(const half8*)&smM[w][pt][ 0 + 8*g];
            const half8 B1 = *(const half8*)&smM[w][pt][32 + 8*g];
            floatx4 a0 = MFMA16x16x32(A0, B0, zz, 0,0,0); a0 = MFMA16x16x32(A1, B1, a0, 0,0,0);
            floatx4 a1 = MFMA16x16x32(A2, B0, zz, 0,0,0); a1 = MFMA16x16x32(A3, B1, a1, 0,0,0);
            floatx4 a2 = MFMA16x16x32(A4, B0, zz, 0,0,0); a2 = MFMA16x16x32(A5, B1, a2, 0,0,0);
            floatx4 a3 = MFMA16x16x32(A6, B0, zz, 0,0,0); a3 = MFMA16x16x32(A7, B1, a3, 0,0,0);
            storeQ(pt, 0, a0); storeQ(pt, 1, a1); storeQ(pt, 2, a2); storeQ(pt, 3, a3);
        }
    }
    asm volatile("" ::: "memory");

    // ===== C2: c2[64] @ wc2 -> color (|.|)
    {
        const half8 A0 = wfrag[18*64+lane], A1 = wfrag[19*64+lane];
        #pragma unroll
        for (int nt = 0; nt < 4; ++nt) {
            const int pt = nt*16 + n;
            const half8 B0 = *(const half8*)&smM[w][pt][ 0 + 8*g];
            const half8 B1 = *(const half8*)&smM[w][pt][32 + 8*g];
            floatx4 acc = MFMA16x16x32(A0, B0, zz, 0,0,0);
            acc = MFMA16x16x32(A1, B1, acc, 0,0,0);
            if (g == 0) out[NPTS + orig[nt]] = fabsf(acc[0]);
        }
    }
}

extern "C" void kernel_launch(void* const* d_in, const int* in_sizes, int n_in,
                              void* d_out, int out_size, void* d_ws, size_t ws_size,
                              hipStream_t stream)
{
    const float* x   = (const float*)d_in[0];
    const float* d   = (const float*)d_in[1];
    const float* emb = (const float*)d_in[2];
    const float* ws0 = (const float*)d_in[3];
    const float* ws1 = (const float*)d_in[4];
    const float* wc0 = (const float*)d_in[5];
    const float* wc1 = (const float*)d_in[6];
    const float* wc2 = (const float*)d_in[7];
    float* out = (float*)d_out;

    // workspace layout (rnk/inv alias the feats region: dead before gather)
    const size_t OFF_WFRAG = 0;
    const size_t OFF_TABU  = 32768;
    const size_t OFF_FEATS = OFF_TABU + 8388608;           // 64 MB
    const size_t OFF_RNK   = OFF_FEATS;                    // alias, 4 MB
    const size_t OFF_INV   = OFF_FEATS + 4194304;          // alias, 4 MB
    const size_t OFF_HIST  = OFF_FEATS + 67108864;         // 128 KB
    const size_t OFF_BOFF  = OFF_HIST + NBUCK*4;           // 128 KB
    const size_t OFF_PD    = OFF_BOFF + NBUCK*4;           // 32 MB
    const size_t NEED_SORT = OFF_PD + (size_t)NPTS*32;
    const size_t NEED_LIN  = OFF_HIST;

    half8* wfrag        = (half8*)((char*)d_ws + OFF_WFRAG);
    unsigned int* tabu  = (unsigned int*)((char*)d_ws + OFF_TABU);
    _Float16* feats     = (_Float16*)((char*)d_ws + OFF_FEATS);
    unsigned int* rnk   = (unsigned int*)((char*)d_ws + OFF_RNK);
    unsigned int* inv   = (unsigned int*)((char*)d_ws + OFF_INV);
    unsigned int* hist  = (unsigned int*)((char*)d_ws + OFF_HIST);
    unsigned int* boff  = (unsigned int*)((char*)d_ws + OFF_BOFF);
    float4* pd          = (float4*)((char*)d_ws + OFF_PD);

    // Replicate numpy's host-side RESOLUTIONS computation bit-for-bit.
    int r[16], off[16];
    const double s = std::exp(std::log(4.0) / 15.0);
    int acc = 0;
    for (int l = 0; l < 16; ++l) {
        r[l] = (int)std::floor(16.0 * std::pow(s, (double)l));
        off[l] = acc;
        acc += (r[l]+1)*(r[l]+1)*(r[l]+1);
    }
    const int4 ra = {r[0],  r[1],  r[2],  r[3]};
    const int4 rb = {r[4],  r[5],  r[6],  r[7]};
    const int4 rc = {r[8],  r[9],  r[10], r[11]};
    const int4 rd = {r[12], r[13], r[14], r[15]};
    const int4 oa = {off[0],  off[1],  off[2],  off[3]};
    const int4 ob = {off[4],  off[5],  off[6],  off[7]};
    const int4 oc = {off[8],  off[9],  off[10], off[11]};
    const int4 od = {off[12], off[13], off[14], off[15]};

    prepack_weights<<<20, 64, 0, stream>>>(ws0, ws1, wc0, wc1, wc2, wfrag);

    const int nmax = (r[15]+1)*(r[15]+1)*(r[15]+1);
    dim3 cgrid((nmax + 255) / 256, 17);   // y==16: hist zero

    if (ws_size >= NEED_SORT) {
        convert_tables<<<cgrid, 256, 0, stream>>>(emb, tabu, hist, 1, ra, rb, rc, rd, oa, ob, oc, od);
        hist_kernel<<<NPTS/256, 256, 0, stream>>>(x, hist, rnk);
        scan_kernel<<<1, 1024, 0, stream>>>(hist, boff);
        inv_kernel<<<NPTS/256, 256, 0, stream>>>(x, boff, rnk, inv);
        permute_kernel<<<NPTS/256, 256, 0, stream>>>(x, d, inv, pd);
        dim3 ggrid(NPTS/256, 4);
        ngp_gather_sorted<<<ggrid, 256, 0, stream>>>(pd, tabu, feats, ra, rb, rc, rd, oa, ob, oc, od);
        ngp_mlp<2><<<NPTS/256, 256, 0, stream>>>(d, feats, pd, wfrag, out);
    } else if (ws_size >= NEED_LIN) {
        convert_tables<<<cgrid, 256, 0, stream>>>(emb, tabu, hist, 0, ra, rb, rc, rd, oa, ob, oc, od);
        ngp_gather_lin<<<NPTS*4/256, 256, 0, stream>>>(x, tabu, feats, ra, rb, rc, rd, oa, ob, oc, od);
        ngp_mlp<0><<<NPTS/256, 256, 0, stream>>>(d, feats, nullptr, wfrag, out);
    }
}

// Round 12
// 183.461 us; speedup vs baseline: 1.2116x; 1.2116x over previous
//
#include <hip/hip_runtime.h>
#include <cmath>

#define NPTS 1048576
#define TABLE_SZ 524288
#define NBUCK 32768   // 32^3 spatial buckets

typedef _Float16 half8 __attribute__((ext_vector_type(8)));
typedef _Float16 half4 __attribute__((ext_vector_type(4)));
typedef _Float16 h2 __attribute__((ext_vector_type(2)));
typedef __fp16 fp16x2 __attribute__((ext_vector_type(2)));
typedef float floatx4 __attribute__((ext_vector_type(4)));
typedef unsigned int uint2a4 __attribute__((ext_vector_type(2), aligned(4)));

#define MFMA16x16x32 __builtin_amdgcn_mfma_f32_16x16x32_f16

__device__ __forceinline__ h2 as_h2(unsigned int u) {
    union { unsigned int u; h2 h; } c; c.u = u; return c.h;
}
__device__ __forceinline__ unsigned int pk_u32(float a, float b) {
    union { fp16x2 h; unsigned int u; } c;
    c.h = __builtin_amdgcn_cvt_pkrtz(a, b);
    return c.u;
}

// ---------------------------------------------------------------------------
// Pre-pack all MLP weights into f16 MFMA A-fragments (W^T as A operand).
// wc0 stored SHIFTED: row16 = 0, rows 17..31 = wc0 rows 16..30.
// ---------------------------------------------------------------------------
__global__ void prepack_weights(const float* __restrict__ ws0,
                                const float* __restrict__ ws1,
                                const float* __restrict__ wc0,
                                const float* __restrict__ wc1,
                                const float* __restrict__ wc2,
                                half8* __restrict__ wfrag)
{
    const int f = blockIdx.x, l = threadIdx.x;
    const int lane_m = l & 15, k0 = (l >> 4) * 8;
    half8 hv;

    if (f >= 6 && f < 10) {               // wc0' (shifted), M=64, K=32
        const int m = 16*(f-6) + lane_m;
        #pragma unroll
        for (int e = 0; e < 8; ++e) {
            const int k = k0 + e;
            float v;
            if (k < 16)       v = wc0[k*64 + m];
            else if (k == 16) v = 0.0f;
            else              v = wc0[(k-1)*64 + m];
            hv[e] = (_Float16)v;
        }
        wfrag[f*64 + l] = hv;
        return;
    }

    const float* W; int Kreal, Mreal, mt, kt;
    if (f < 4)       { W = ws0; Kreal = 32; Mreal = 64; mt = f;          kt = 0;        }
    else if (f < 6)  { W = ws1; Kreal = 64; Mreal = 16; mt = 0;          kt = f - 4;    }
    else if (f < 18) { W = wc1; Kreal = 64; Mreal = 64; mt = (f-10)>>1;  kt = (f-10)&1; }
    else             { W = wc2; Kreal = 64; Mreal = 1;  mt = 0;          kt = f - 18;   }

    const int m  = 16*mt + lane_m;
    const int kk0 = 32*kt + k0;
    #pragma unroll
    for (int e = 0; e < 8; ++e) {
        const int k = kk0 + e;
        const float v = (m < Mreal && k < Kreal) ? W[k*Mreal + m] : 0.0f;
        hv[e] = (_Float16)v;
    }
    wfrag[f*64 + l] = hv;
}

// ---------------------------------------------------------------------------
// Convert ACTIVE region of each level's fp32 table to packed f16.
// blockIdx.y==16 zeroes the histogram.
// ---------------------------------------------------------------------------
__global__ __launch_bounds__(256) void convert_tables(
    const float* __restrict__ emb, unsigned int* __restrict__ tabu,
    unsigned int* __restrict__ hist, int zero_hist,
    int4 ra, int4 rb, int4 rc, int4 rd,
    int4 oa, int4 ob, int4 oc, int4 od)
{
    const int l = blockIdx.y;
    if (l == 16) {
        if (zero_hist) {
            const int e = blockIdx.x * 256 + threadIdx.x;
            if (e < NBUCK) hist[e] = 0u;
        }
        return;
    }
    const int q = l >> 2, j = l & 3;
    const int4 rv = (q == 0) ? ra : (q == 1) ? rb : (q == 2) ? rc : rd;
    const int4 ov = (q == 0) ? oa : (q == 1) ? ob : (q == 2) ? oc : od;
    const int R   = (j == 0) ? rv.x : (j == 1) ? rv.y : (j == 2) ? rv.z : rv.w;
    const int off = (j == 0) ? ov.x : (j == 1) ? ov.y : (j == 2) ? ov.z : ov.w;
    const int n = (R+1)*(R+1)*(R+1);
    const int e = blockIdx.x * 256 + threadIdx.x;
    if (e >= n) return;
    const float2 v = *(const float2*)(emb + (size_t)l * (TABLE_SZ*2) + 2*(size_t)e);
    tabu[off + e] = pk_u32(v.x, v.y);
}

// ---------------------------------------------------------------------------
// Spatial counting sort (32^3 buckets)
// ---------------------------------------------------------------------------
__device__ __forceinline__ int bucket_of(float px, float py, float pz) {
    int bx = (int)(px * 32.0f); bx = bx < 0 ? 0 : (bx > 31 ? 31 : bx);
    int by = (int)(py * 32.0f); by = by < 0 ? 0 : (by > 31 ? 31 : by);
    int bz = (int)(pz * 32.0f); bz = bz < 0 ? 0 : (bz > 31 ? 31 : bz);
    return bx | (by << 5) | (bz << 10);
}

__global__ __launch_bounds__(256) void hist_kernel(
    const float* __restrict__ xin, unsigned int* __restrict__ hist,
    unsigned int* __restrict__ rnk)
{
    const int i = blockIdx.x * 256 + threadIdx.x;
    const float px = (xin[3*i+0] + 1.0f) * 0.5f;
    const float py = (xin[3*i+1] + 1.0f) * 0.5f;
    const float pz = (xin[3*i+2] + 1.0f) * 0.5f;
    rnk[i] = atomicAdd(&hist[bucket_of(px, py, pz)], 1u);
}

__global__ __launch_bounds__(1024) void scan_kernel(
    const unsigned int* __restrict__ hist, unsigned int* __restrict__ off)
{
    __shared__ unsigned int ssum[1024];
    const int t = threadIdx.x;
    unsigned int v[32];
    unsigned int s = 0;
    #pragma unroll
    for (int j = 0; j < 32; ++j) {
        const unsigned int h = hist[t*32 + j];
        v[j] = s; s += h;
    }
    ssum[t] = s;
    __syncthreads();
    for (int d = 1; d < 1024; d <<= 1) {
        const unsigned int add = (t >= d) ? ssum[t-d] : 0u;
        __syncthreads();
        ssum[t] += add;
        __syncthreads();
    }
    const unsigned int base = (t == 0) ? 0u : ssum[t-1];
    #pragma unroll
    for (int j = 0; j < 32; ++j) off[t*32 + j] = base + v[j];
}

// direct scatter of ONE interleaved 32B record per point:
// pd[2pos]   = {px,py,pz, -}      pd[2pos+1] = {dx,dy,dz, orig}
// Both stores hit the SAME 128B line -> 1 line touch per point (vs 2 with
// separate xs4/ds4 arrays in the round-10 variant).
__global__ __launch_bounds__(256) void scatter_pd(
    const float* __restrict__ xin, const float* __restrict__ din,
    const unsigned int* __restrict__ boff, const unsigned int* __restrict__ rnk,
    float4* __restrict__ pd)
{
    const int i = blockIdx.x * 256 + threadIdx.x;
    const float px = (xin[3*i+0] + 1.0f) * 0.5f;
    const float py = (xin[3*i+1] + 1.0f) * 0.5f;
    const float pz = (xin[3*i+2] + 1.0f) * 0.5f;
    const int b = bucket_of(px, py, pz);
    const unsigned int pos = boff[b] + rnk[i];
    const float dx = din[3*i+0], dy = din[3*i+1], dz = din[3*i+2];
    pd[2*(size_t)pos]     = make_float4(px, py, pz, 0.0f);
    pd[2*(size_t)pos + 1] = make_float4(dx, dy, dz, __uint_as_float((unsigned int)i));
}

// ---------------------------------------------------------------------------
// Gather over SORTED points, LEVEL-MAJOR (q = blockIdx.y). Feats SoA in
// SORTED order: feats[q*NPTS + p] (half8). Position from pd[2p].
// ---------------------------------------------------------------------------
__global__ __launch_bounds__(256, 4) void ngp_gather_sorted(
    const float4* __restrict__ pd, const unsigned int* __restrict__ tabu,
    _Float16* __restrict__ feats,
    int4 ra, int4 rb, int4 rc, int4 rd,
    int4 oa, int4 ob, int4 oc, int4 od)
{
    const int p = blockIdx.x * 256 + threadIdx.x;
    const int q = blockIdx.y;

    const float4 xv = pd[2*(size_t)p];
    const float px = xv.x, py = xv.y, pz = xv.z;

    const int4 rv = (q == 0) ? ra : (q == 1) ? rb : (q == 2) ? rc : rd;
    const int4 ov = (q == 0) ? oa : (q == 1) ? ob : (q == 2) ? oc : od;

    uint2a4 P[16];
    float fx[4], fy[4], fz[4];

    #pragma unroll
    for (int j = 0; j < 4; ++j) {
        const int R   = (j == 0) ? rv.x : (j == 1) ? rv.y : (j == 2) ? rv.z : rv.w;
        const int off = (j == 0) ? ov.x : (j == 1) ? ov.y : (j == 2) ? ov.z : ov.w;
        const float Rf = (float)R;
        const float gx = px*Rf, gy = py*Rf, gz = pz*Rf;
        int x0 = (int)floorf(gx); x0 = x0 < 0 ? 0 : (x0 > R-1 ? R-1 : x0);
        int y0 = (int)floorf(gy); y0 = y0 < 0 ? 0 : (y0 > R-1 ? R-1 : y0);
        int z0 = (int)floorf(gz); z0 = z0 < 0 ? 0 : (z0 > R-1 ? R-1 : z0);
        fx[j] = gx - (float)x0; fy[j] = gy - (float)y0; fz[j] = gz - (float)z0;
        const int s1 = R + 1, s2 = s1 * s1;
        const unsigned int* tab = tabu + off;
        const int b = x0 + y0*s1 + z0*s2;
        P[4*j+0] = *(const uint2a4*)(tab + b);
        P[4*j+1] = *(const uint2a4*)(tab + b + s1);
        P[4*j+2] = *(const uint2a4*)(tab + b + s2);
        P[4*j+3] = *(const uint2a4*)(tab + b + s1 + s2);
    }

    union { half8 v; h2 h[4]; } hv;
    #pragma unroll
    for (int j = 0; j < 4; ++j) {
        const _Float16 fxh = (_Float16)fx[j];
        const _Float16 fyh = (_Float16)fy[j];
        const _Float16 fzh = (_Float16)fz[j];
        const h2 fx2 = {fxh, fxh}, fy2 = {fyh, fyh}, fz2 = {fzh, fzh};
        const h2 c000 = as_h2(P[4*j+0].x), c100 = as_h2(P[4*j+0].y);
        const h2 c010 = as_h2(P[4*j+1].x), c110 = as_h2(P[4*j+1].y);
        const h2 c001 = as_h2(P[4*j+2].x), c101 = as_h2(P[4*j+2].y);
        const h2 c011 = as_h2(P[4*j+3].x), c111 = as_h2(P[4*j+3].y);
        const h2 a00 = c000 + fx2 * (c100 - c000);
        const h2 a10 = c010 + fx2 * (c110 - c010);
        const h2 a01 = c001 + fx2 * (c101 - c001);
        const h2 a11 = c011 + fx2 * (c111 - c011);
        const h2 b0  = a00 + fy2 * (a10 - a00);
        const h2 b1  = a01 + fy2 * (a11 - a01);
        hv.h[j] = b0 + fz2 * (b1 - b0);
    }
    *(half8*)&feats[((size_t)q * NPTS + p) * 8] = hv.v;
}

// ---------------------------------------------------------------------------
// Unsorted gather (tier-0 fallback, f16 tables, AoS feats in orig order).
// ---------------------------------------------------------------------------
__global__ __launch_bounds__(256, 4) void ngp_gather_lin(
    const float* __restrict__ xin, const unsigned int* __restrict__ tabu,
    _Float16* __restrict__ feats,
    int4 ra, int4 rb, int4 rc, int4 rd,
    int4 oa, int4 ob, int4 oc, int4 od)
{
    const int tid = blockIdx.x * 256 + threadIdx.x;
    const int p = tid >> 2;
    const int q = tid & 3;

    const float px = (xin[3*p+0] + 1.0f) * 0.5f;
    const float py = (xin[3*p+1] + 1.0f) * 0.5f;
    const float pz = (xin[3*p+2] + 1.0f) * 0.5f;

    const int4 rv = (q == 0) ? ra : (q == 1) ? rb : (q == 2) ? rc : rd;
    const int4 ov = (q == 0) ? oa : (q == 1) ? ob : (q == 2) ? oc : od;

    uint2a4 P[16];
    float fx[4], fy[4], fz[4];
    #pragma unroll
    for (int j = 0; j < 4; ++j) {
        const int R   = (j == 0) ? rv.x : (j == 1) ? rv.y : (j == 2) ? rv.z : rv.w;
        const int off = (j == 0) ? ov.x : (j == 1) ? ov.y : (j == 2) ? ov.z : ov.w;
        const float Rf = (float)R;
        const float gx = px*Rf, gy = py*Rf, gz = pz*Rf;
        int x0 = (int)floorf(gx); x0 = x0 < 0 ? 0 : (x0 > R-1 ? R-1 : x0);
        int y0 = (int)floorf(gy); y0 = y0 < 0 ? 0 : (y0 > R-1 ? R-1 : y0);
        int z0 = (int)floorf(gz); z0 = z0 < 0 ? 0 : (z0 > R-1 ? R-1 : z0);
        fx[j] = gx - (float)x0; fy[j] = gy - (float)y0; fz[j] = gz - (float)z0;
        const int s1 = R + 1, s2 = s1 * s1;
        const unsigned int* tab = tabu + off;
        const int b = x0 + y0*s1 + z0*s2;
        P[4*j+0] = *(const uint2a4*)(tab + b);
        P[4*j+1] = *(const uint2a4*)(tab + b + s1);
        P[4*j+2] = *(const uint2a4*)(tab + b + s2);
        P[4*j+3] = *(const uint2a4*)(tab + b + s1 + s2);
    }
    union { half8 v; h2 h[4]; } hv;
    #pragma unroll
    for (int j = 0; j < 4; ++j) {
        const _Float16 fxh = (_Float16)fx[j];
        const _Float16 fyh = (_Float16)fy[j];
        const _Float16 fzh = (_Float16)fz[j];
        const h2 fx2 = {fxh, fxh}, fy2 = {fyh, fyh}, fz2 = {fzh, fzh};
        const h2 c000 = as_h2(P[4*j+0].x), c100 = as_h2(P[4*j+0].y);
        const h2 c010 = as_h2(P[4*j+1].x), c110 = as_h2(P[4*j+1].y);
        const h2 c001 = as_h2(P[4*j+2].x), c101 = as_h2(P[4*j+2].y);
        const h2 c011 = as_h2(P[4*j+3].x), c111 = as_h2(P[4*j+3].y);
        const h2 a00 = c000 + fx2 * (c100 - c000);
        const h2 a10 = c010 + fx2 * (c110 - c010);
        const h2 a01 = c001 + fx2 * (c101 - c001);
        const h2 a11 = c011 + fx2 * (c111 - c011);
        const h2 b0  = a00 + fy2 * (a10 - a00);
        const h2 b1  = a01 + fy2 * (a11 - a01);
        hv.h[j] = b0 + fz2 * (b1 - b0);
    }
    *(half8*)&feats[(size_t)p*32 + q*8] = hv.v;
}

// ---------------------------------------------------------------------------
// MLP kernel. 4 waves/block, 64 points/wave (nt=0..3), wave-private LDS.
// MODE 2: sorted, fully-coalesced loads (pd[2p+1] carries dir+orig).
// MODE 0: unsorted AoS feats.
// Scattered OUT stores are fire-and-forget (no wave stall).
// ---------------------------------------------------------------------------
template<int MODE>
__global__ __launch_bounds__(256) void ngp_mlp(
    const float* __restrict__ din, const _Float16* __restrict__ feats,
    const float4* __restrict__ pd,
    const half8* __restrict__ wfrag, float* __restrict__ out)
{
    __shared__ __align__(16) _Float16 smM[4][64][72];  // H / c1 / c2

    const int tid  = threadIdx.x;
    const int w    = tid >> 6, lane = tid & 63;
    const int gbase = (blockIdx.x * 4 + w) * 64;

    const int n = lane & 15, g = lane >> 4;
    const floatx4 zz = {0.f, 0.f, 0.f, 0.f};

    // per-nt point data: orig index + direction (coalesced in MODE 2)
    unsigned int orig[4];
    float dX[4], dY[4], dZ[4];
    #pragma unroll
    for (int nt = 0; nt < 4; ++nt) {
        const int pt = nt*16 + n;
        if (MODE == 2) {
            const float4 dv = pd[2*(size_t)(gbase + pt) + 1];
            dX[nt] = dv.x; dY[nt] = dv.y; dZ[nt] = dv.z;
            orig[nt] = __float_as_uint(dv.w);
        } else {
            orig[nt] = gbase + pt;
            dX[nt] = din[3*orig[nt]+0]; dY[nt] = din[3*orig[nt]+1]; dZ[nt] = din[3*orig[nt]+2];
        }
    }

    auto storeQ = [&](int pt, int mt, floatx4 a) {   // relu + packed f16
        union { unsigned int u[2]; half4 v; } c;
        c.u[0] = pk_u32(fmaxf(a[0], 0.f), fmaxf(a[1], 0.f));
        c.u[1] = pk_u32(fmaxf(a[2], 0.f), fmaxf(a[3], 0.f));
        *(half4*)&smM[w][pt][16*mt + 4*g] = c.v;
    };

    // ===== S0: feats[32] @ ws0 -> H[64], relu
    {
        const half8 A0 = wfrag[0*64+lane], A1 = wfrag[1*64+lane];
        const half8 A2 = wfrag[2*64+lane], A3 = wfrag[3*64+lane];
        #pragma unroll
        for (int nt = 0; nt < 4; ++nt) {
            const int pt = nt*16 + n;
            half8 B;
            if (MODE == 2)
                B = *(const half8*)&feats[((size_t)g * NPTS + (gbase + pt)) * 8];
            else
                B = *(const half8*)&feats[(size_t)(gbase + pt)*32 + 8*g];
            floatx4 a0 = MFMA16x16x32(A0, B, zz, 0,0,0);
            floatx4 a1 = MFMA16x16x32(A1, B, zz, 0,0,0);
            floatx4 a2 = MFMA16x16x32(A2, B, zz, 0,0,0);
            floatx4 a3 = MFMA16x16x32(A3, B, zz, 0,0,0);
            storeQ(pt, 0, a0); storeQ(pt, 1, a1); storeQ(pt, 2, a2); storeQ(pt, 3, a3);
        }
    }
    asm volatile("" ::: "memory");

    // ===== S1: H[64] @ ws1 -> G[16] (linear). sigma out; geo words in regs.
    unsigned int s1a[4], s1b[4];
    {
        const half8 A0 = wfrag[4*64+lane], A1 = wfrag[5*64+lane];
        #pragma unroll
        for (int nt = 0; nt < 4; ++nt) {
            const int pt = nt*16 + n;
            const half8 B0 = *(const half8*)&smM[w][pt][ 0 + 8*g];
            const half8 B1 = *(const half8*)&smM[w][pt][32 + 8*g];
            floatx4 acc = MFMA16x16x32(A0, B0, zz, 0,0,0);
            acc = MFMA16x16x32(A1, B1, acc, 0,0,0);
            s1a[nt] = pk_u32(acc[0], acc[1]);
            s1b[nt] = pk_u32(acc[2], acc[3]);
            if (g == 0) out[orig[nt]] = fabsf(acc[0]);   // sigma
        }
    }
    asm volatile("" ::: "memory");

    // ===== C0: hd'[32] @ wc0' -> c1[64], relu
    // hd' = [SH(16) ; g0..g15]; geo B via 4 shfls from S1 words.
    {
        const half8 A0 = wfrag[6*64+lane], A1 = wfrag[7*64+lane];
        const half8 A2 = wfrag[8*64+lane], A3 = wfrag[9*64+lane];
        const int srcA = ((g & 1) << 5) + n;
        #pragma unroll
        for (int nt = 0; nt < 4; ++nt) {
            const int pt = nt*16 + n;
            const unsigned int w0 = __shfl(s1a[nt], srcA);
            const unsigned int w1 = __shfl(s1b[nt], srcA);
            const unsigned int w2 = __shfl(s1a[nt], srcA + 16);
            const unsigned int w3 = __shfl(s1b[nt], srcA + 16);
            union { half8 v; unsigned int u[4]; } B;
            if (g < 2) {
                const float x = dX[nt], y = dY[nt], z = dZ[nt];
                const float xx = x*x, yy = y*y, zzq = z*z;
                const float xy = x*y, yz = y*z, xz = x*z;
                float s[8];
                if (g == 0) {
                    s[0] = 0.28209479177387814f;
                    s[1] = -0.48860251190291987f * y;
                    s[2] =  0.48860251190291987f * z;
                    s[3] = -0.48860251190291987f * x;
                    s[4] =  1.0925484305920792f * xy;
                    s[5] = -1.0925484305920792f * yz;
                    s[6] =  0.94617469575756f * zzq - 0.31539156525252005f;
                    s[7] = -1.0925484305920792f * xz;
                } else {
                    s[0] =  0.5462742152960396f * (xx - yy);
                    s[1] =  0.5900435899266435f * y * (yy - 3.0f*xx);
                    s[2] =  2.890611442640554f * xy * z;
                    s[3] =  0.4570457994644657f * y * (1.0f - 5.0f*zzq);
                    s[4] =  0.3731763325901154f * z * (5.0f*zzq - 3.0f);
                    s[5] =  0.4570457994644657f * x * (1.0f - 5.0f*zzq);
                    s[6] =  1.445305721320277f * z * (xx - yy);
                    s[7] =  0.5900435899266435f * x * (3.0f*yy - xx);
                }
                B.u[0] = pk_u32(s[0], s[1]); B.u[1] = pk_u32(s[2], s[3]);
                B.u[2] = pk_u32(s[4], s[5]); B.u[3] = pk_u32(s[6], s[7]);
            } else {
                B.u[0] = w0; B.u[1] = w1; B.u[2] = w2; B.u[3] = w3;
            }
            floatx4 a0 = MFMA16x16x32(A0, B.v, zz, 0,0,0);
            floatx4 a1 = MFMA16x16x32(A1, B.v, zz, 0,0,0);
            floatx4 a2 = MFMA16x16x32(A2, B.v, zz, 0,0,0);
            floatx4 a3 = MFMA16x16x32(A3, B.v, zz, 0,0,0);
            storeQ(pt, 0, a0); storeQ(pt, 1, a1); storeQ(pt, 2, a2); storeQ(pt, 3, a3);
        }
    }
    asm volatile("" ::: "memory");

    // ===== C1: c1[64] @ wc1 -> c2[64], relu
    {
        const half8 A0 = wfrag[10*64+lane], A1 = wfrag[11*64+lane];
        const half8 A2 = wfrag[12*64+lane], A3 = wfrag[13*64+lane];
        const half8 A4 = wfrag[14*64+lane], A5 = wfrag[15*64+lane];
        const half8 A6 = wfrag[16*64+lane], A7 = wfrag[17*64+lane];
        #pragma unroll
        for (int nt = 0; nt < 4; ++nt) {
            const int pt = nt*16 + n;
            const half8 B0 = *(const half8*)&smM[w][pt][ 0 + 8*g];
            const half8 B1 = *(const half8*)&smM[w][pt][32 + 8*g];
            floatx4 a0 = MFMA16x16x32(A0, B0, zz, 0,0,0); a0 = MFMA16x16x32(A1, B1, a0, 0,0,0);
            floatx4 a1 = MFMA16x16x32(A2, B0, zz, 0,0,0); a1 = MFMA16x16x32(A3, B1, a1, 0,0,0);
            floatx4 a2 = MFMA16x16x32(A4, B0, zz, 0,0,0); a2 = MFMA16x16x32(A5, B1, a2, 0,0,0);
            floatx4 a3 = MFMA16x16x32(A6, B0, zz, 0,0,0); a3 = MFMA16x16x32(A7, B1, a3, 0,0,0);
            storeQ(pt, 0, a0); storeQ(pt, 1, a1); storeQ(pt, 2, a2); storeQ(pt, 3, a3);
        }
    }
    asm volatile("" ::: "memory");

    // ===== C2: c2[64] @ wc2 -> color (|.|)
    {
        const half8 A0 = wfrag[18*64+lane], A1 = wfrag[19*64+lane];
        #pragma unroll
        for (int nt = 0; nt < 4; ++nt) {
            const int pt = nt*16 + n;
            const half8 B0 = *(const half8*)&smM[w][pt][ 0 + 8*g];
            const half8 B1 = *(const half8*)&smM[w][pt][32 + 8*g];
            floatx4 acc = MFMA16x16x32(A0, B0, zz, 0,0,0);
            acc = MFMA16x16x32(A1, B1, acc, 0,0,0);
            if (g == 0) out[NPTS + orig[nt]] = fabsf(acc[0]);
        }
    }
}

extern "C" void kernel_launch(void* const* d_in, const int* in_sizes, int n_in,
                              void* d_out, int out_size, void* d_ws, size_t ws_size,
                              hipStream_t stream)
{
    const float* x   = (const float*)d_in[0];
    const float* d   = (const float*)d_in[1];
    const float* emb = (const float*)d_in[2];
    const float* ws0 = (const float*)d_in[3];
    const float* ws1 = (const float*)d_in[4];
    const float* wc0 = (const float*)d_in[5];
    const float* wc1 = (const float*)d_in[6];
    const float* wc2 = (const float*)d_in[7];
    float* out = (float*)d_out;

    // workspace layout (rnk aliases the feats region: dead before gather)
    const size_t OFF_WFRAG = 0;
    const size_t OFF_TABU  = 32768;
    const size_t OFF_FEATS = OFF_TABU + 8388608;           // 64 MB
    const size_t OFF_RNK   = OFF_FEATS;                    // alias, 4 MB
    const size_t OFF_HIST  = OFF_FEATS + 67108864;         // 128 KB
    const size_t OFF_BOFF  = OFF_HIST + NBUCK*4;           // 128 KB
    const size_t OFF_PD    = OFF_BOFF + NBUCK*4;           // 32 MB
    const size_t NEED_SORT = OFF_PD + (size_t)NPTS*32;
    const size_t NEED_LIN  = OFF_HIST;

    half8* wfrag        = (half8*)((char*)d_ws + OFF_WFRAG);
    unsigned int* tabu  = (unsigned int*)((char*)d_ws + OFF_TABU);
    _Float16* feats     = (_Float16*)((char*)d_ws + OFF_FEATS);
    unsigned int* rnk   = (unsigned int*)((char*)d_ws + OFF_RNK);
    unsigned int* hist  = (unsigned int*)((char*)d_ws + OFF_HIST);
    unsigned int* boff  = (unsigned int*)((char*)d_ws + OFF_BOFF);
    float4* pd          = (float4*)((char*)d_ws + OFF_PD);

    // Replicate numpy's host-side RESOLUTIONS computation bit-for-bit.
    int r[16], off[16];
    const double s = std::exp(std::log(4.0) / 15.0);
    int acc = 0;
    for (int l = 0; l < 16; ++l) {
        r[l] = (int)std::floor(16.0 * std::pow(s, (double)l));
        off[l] = acc;
        acc += (r[l]+1)*(r[l]+1)*(r[l]+1);
    }
    const int4 ra = {r[0],  r[1],  r[2],  r[3]};
    const int4 rb = {r[4],  r[5],  r[6],  r[7]};
    const int4 rc = {r[8],  r[9],  r[10], r[11]};
    const int4 rd = {r[12], r[13], r[14], r[15]};
    const int4 oa = {off[0],  off[1],  off[2],  off[3]};
    const int4 ob = {off[4],  off[5],  off[6],  off[7]};
    const int4 oc = {off[8],  off[9],  off[10], off[11]};
    const int4 od = {off[12], off[13], off[14], off[15]};

    prepack_weights<<<20, 64, 0, stream>>>(ws0, ws1, wc0, wc1, wc2, wfrag);

    const int nmax = (r[15]+1)*(r[15]+1)*(r[15]+1);
    dim3 cgrid((nmax + 255) / 256, 17);   // y==16: hist zero

    if (ws_size >= NEED_SORT) {
        convert_tables<<<cgrid, 256, 0, stream>>>(emb, tabu, hist, 1, ra, rb, rc, rd, oa, ob, oc, od);
        hist_kernel<<<NPTS/256, 256, 0, stream>>>(x, hist, rnk);
        scan_kernel<<<1, 1024, 0, stream>>>(hist, boff);
        scatter_pd<<<NPTS/256, 256, 0, stream>>>(x, d, boff, rnk, pd);
        dim3 ggrid(NPTS/256, 4);
        ngp_gather_sorted<<<ggrid, 256, 0, stream>>>(pd, tabu, feats, ra, rb, rc, rd, oa, ob, oc, od);
        ngp_mlp<2><<<NPTS/256, 256, 0, stream>>>(d, feats, pd, wfrag, out);
    } else if (ws_size >= NEED_LIN) {
        convert_tables<<<cgrid, 256, 0, stream>>>(emb, tabu, hist, 0, ra, rb, rc, rd, oa, ob, oc, od);
        ngp_gather_lin<<<NPTS*4/256, 256, 0, stream>>>(x, tabu, feats, ra, rb, rc, rd, oa, ob, oc, od);
        ngp_mlp<0><<<NPTS/256, 256, 0, stream>>>(d, feats, nullptr, wfrag, out);
    }
}

// Round 13
// 171.086 us; speedup vs baseline: 1.2992x; 1.0723x over previous
//
#include <hip/hip_runtime.h>
#include <cmath>

#define NPTS 1048576
#define TABLE_SZ 524288
#define NBUCK 32768   // 32^3 spatial buckets

typedef _Float16 half8 __attribute__((ext_vector_type(8)));
typedef _Float16 half4 __attribute__((ext_vector_type(4)));
typedef _Float16 h2 __attribute__((ext_vector_type(2)));
typedef __fp16 fp16x2 __attribute__((ext_vector_type(2)));
typedef float floatx4 __attribute__((ext_vector_type(4)));
typedef unsigned int uint2a4 __attribute__((ext_vector_type(2), aligned(4)));

#define MFMA16x16x32 __builtin_amdgcn_mfma_f32_16x16x32_f16

__device__ __forceinline__ h2 as_h2(unsigned int u) {
    union { unsigned int u; h2 h; } c; c.u = u; return c.h;
}
__device__ __forceinline__ unsigned int pk_u32(float a, float b) {
    union { fp16x2 h; unsigned int u; } c;
    c.h = __builtin_amdgcn_cvt_pkrtz(a, b);
    return c.u;
}

// ---------------------------------------------------------------------------
// Pre-pack all MLP weights into f16 MFMA A-fragments (W^T as A operand).
// wc0 stored SHIFTED: row16 = 0, rows 17..31 = wc0 rows 16..30.
// ---------------------------------------------------------------------------
__global__ void prepack_weights(const float* __restrict__ ws0,
                                const float* __restrict__ ws1,
                                const float* __restrict__ wc0,
                                const float* __restrict__ wc1,
                                const float* __restrict__ wc2,
                                half8* __restrict__ wfrag)
{
    const int f = blockIdx.x, l = threadIdx.x;
    const int lane_m = l & 15, k0 = (l >> 4) * 8;
    half8 hv;

    if (f >= 6 && f < 10) {               // wc0' (shifted), M=64, K=32
        const int m = 16*(f-6) + lane_m;
        #pragma unroll
        for (int e = 0; e < 8; ++e) {
            const int k = k0 + e;
            float v;
            if (k < 16)       v = wc0[k*64 + m];
            else if (k == 16) v = 0.0f;
            else              v = wc0[(k-1)*64 + m];
            hv[e] = (_Float16)v;
        }
        wfrag[f*64 + l] = hv;
        return;
    }

    const float* W; int Kreal, Mreal, mt, kt;
    if (f < 4)       { W = ws0; Kreal = 32; Mreal = 64; mt = f;          kt = 0;        }
    else if (f < 6)  { W = ws1; Kreal = 64; Mreal = 16; mt = 0;          kt = f - 4;    }
    else if (f < 18) { W = wc1; Kreal = 64; Mreal = 64; mt = (f-10)>>1;  kt = (f-10)&1; }
    else             { W = wc2; Kreal = 64; Mreal = 1;  mt = 0;          kt = f - 18;   }

    const int m  = 16*mt + lane_m;
    const int kk0 = 32*kt + k0;
    #pragma unroll
    for (int e = 0; e < 8; ++e) {
        const int k = kk0 + e;
        const float v = (m < Mreal && k < Kreal) ? W[k*Mreal + m] : 0.0f;
        hv[e] = (_Float16)v;
    }
    wfrag[f*64 + l] = hv;
}

// ---------------------------------------------------------------------------
// Convert ACTIVE region of each level's fp32 table to packed f16.
// blockIdx.y==16 zeroes the histogram.
// ---------------------------------------------------------------------------
__global__ __launch_bounds__(256) void convert_tables(
    const float* __restrict__ emb, unsigned int* __restrict__ tabu,
    unsigned int* __restrict__ hist, int zero_hist,
    int4 ra, int4 rb, int4 rc, int4 rd,
    int4 oa, int4 ob, int4 oc, int4 od)
{
    const int l = blockIdx.y;
    if (l == 16) {
        if (zero_hist) {
            const int e = blockIdx.x * 256 + threadIdx.x;
            if (e < NBUCK) hist[e] = 0u;
        }
        return;
    }
    const int q = l >> 2, j = l & 3;
    const int4 rv = (q == 0) ? ra : (q == 1) ? rb : (q == 2) ? rc : rd;
    const int4 ov = (q == 0) ? oa : (q == 1) ? ob : (q == 2) ? oc : od;
    const int R   = (j == 0) ? rv.x : (j == 1) ? rv.y : (j == 2) ? rv.z : rv.w;
    const int off = (j == 0) ? ov.x : (j == 1) ? ov.y : (j == 2) ? ov.z : ov.w;
    const int n = (R+1)*(R+1)*(R+1);
    const int e = blockIdx.x * 256 + threadIdx.x;
    if (e >= n) return;
    const float2 v = *(const float2*)(emb + (size_t)l * (TABLE_SZ*2) + 2*(size_t)e);
    tabu[off + e] = pk_u32(v.x, v.y);
}

// ---------------------------------------------------------------------------
// Spatial counting sort (32^3 buckets)
// ---------------------------------------------------------------------------
__device__ __forceinline__ int bucket_of(float px, float py, float pz) {
    int bx = (int)(px * 32.0f); bx = bx < 0 ? 0 : (bx > 31 ? 31 : bx);
    int by = (int)(py * 32.0f); by = by < 0 ? 0 : (by > 31 ? 31 : by);
    int bz = (int)(pz * 32.0f); bz = bz < 0 ? 0 : (bz > 31 ? 31 : bz);
    return bx | (by << 5) | (bz << 10);
}

__global__ __launch_bounds__(256) void hist_kernel(
    const float* __restrict__ xin, unsigned int* __restrict__ hist,
    unsigned int* __restrict__ rnk)
{
    const int i = blockIdx.x * 256 + threadIdx.x;
    const float px = (xin[3*i+0] + 1.0f) * 0.5f;
    const float py = (xin[3*i+1] + 1.0f) * 0.5f;
    const float pz = (xin[3*i+2] + 1.0f) * 0.5f;
    rnk[i] = atomicAdd(&hist[bucket_of(px, py, pz)], 1u);
}

__global__ __launch_bounds__(1024) void scan_kernel(
    const unsigned int* __restrict__ hist, unsigned int* __restrict__ off)
{
    __shared__ unsigned int ssum[1024];
    const int t = threadIdx.x;
    unsigned int v[32];
    unsigned int s = 0;
    #pragma unroll
    for (int j = 0; j < 32; ++j) {
        const unsigned int h = hist[t*32 + j];
        v[j] = s; s += h;
    }
    ssum[t] = s;
    __syncthreads();
    for (int d = 1; d < 1024; d <<= 1) {
        const unsigned int add = (t >= d) ? ssum[t-d] : 0u;
        __syncthreads();
        ssum[t] += add;
        __syncthreads();
    }
    const unsigned int base = (t == 0) ? 0u : ssum[t-1];
    #pragma unroll
    for (int j = 0; j < 32; ++j) off[t*32 + j] = base + v[j];
}

// direct scatter of ONE interleaved 32B record per point:
// pd[2pos]   = {px,py,pz, -}      pd[2pos+1] = {dx,dy,dz, orig}
__global__ __launch_bounds__(256) void scatter_pd(
    const float* __restrict__ xin, const float* __restrict__ din,
    const unsigned int* __restrict__ boff, const unsigned int* __restrict__ rnk,
    float4* __restrict__ pd)
{
    const int i = blockIdx.x * 256 + threadIdx.x;
    const float px = (xin[3*i+0] + 1.0f) * 0.5f;
    const float py = (xin[3*i+1] + 1.0f) * 0.5f;
    const float pz = (xin[3*i+2] + 1.0f) * 0.5f;
    const int b = bucket_of(px, py, pz);
    const unsigned int pos = boff[b] + rnk[i];
    const float dx = din[3*i+0], dy = din[3*i+1], dz = din[3*i+2];
    pd[2*(size_t)pos]     = make_float4(px, py, pz, 0.0f);
    pd[2*(size_t)pos + 1] = make_float4(dx, dy, dz, __uint_as_float((unsigned int)i));
}

// ---------------------------------------------------------------------------
// FUSED gather+MLP over SORTED points. 256 pts/block, 4 waves.
// Phase A: wave w gathers level-quad q=w for all 256 block points (level-
//   uniform wave loads, as in the split gather), writing feats to LDS
//   fls[256][40] (stride 40 halfs = 80B: 16B-aligned, conflict-minimal).
// Handoff: barrier -> each lane picks its 4 S0 B-frags to regs -> barrier.
// Phase B: MLP (round-12 MODE 2), smM aliases fls storage (dead by then).
// ---------------------------------------------------------------------------
__global__ __launch_bounds__(256) void ngp_fused_sorted(
    const float4* __restrict__ pd, const unsigned int* __restrict__ tabu,
    const half8* __restrict__ wfrag, float* __restrict__ out,
    int4 ra, int4 rb, int4 rc, int4 rd,
    int4 oa, int4 ob, int4 oc, int4 od)
{
    __shared__ __align__(16) _Float16 smM[4][64][72];   // 36.9 KB
    _Float16* fls = (_Float16*)smM;                     // [256][40], 20 KB alias

    const int tid  = threadIdx.x;
    const int w    = tid >> 6, lane = tid & 63;
    const int pblock = blockIdx.x * 256;
    const int n = lane & 15, g = lane >> 4;
    const int gbase = pblock + w * 64;
    const floatx4 zz = {0.f, 0.f, 0.f, 0.f};

    // early coalesced loads: dir + orig for Phase B
    unsigned int orig[4];
    float dX[4], dY[4], dZ[4];
    #pragma unroll
    for (int nt = 0; nt < 4; ++nt) {
        const float4 dv = pd[2*(size_t)(gbase + nt*16 + n) + 1];
        dX[nt] = dv.x; dY[nt] = dv.y; dZ[nt] = dv.z;
        orig[nt] = __float_as_uint(dv.w);
    }

    // ================= Phase A: gather (wave-uniform quad q = w)
    {
        const int q = w;
        const int4 rv = (q == 0) ? ra : (q == 1) ? rb : (q == 2) ? rc : rd;
        const int4 ov = (q == 0) ? oa : (q == 1) ? ob : (q == 2) ? oc : od;
        #pragma unroll 2
        for (int it = 0; it < 4; ++it) {
            const int pl = it*64 + lane;
            const float4 xv = pd[2*(size_t)(pblock + pl)];
            const float px = xv.x, py = xv.y, pz = xv.z;

            uint2a4 P[16];
            float fx[4], fy[4], fz[4];
            #pragma unroll
            for (int j = 0; j < 4; ++j) {
                const int R   = (j == 0) ? rv.x : (j == 1) ? rv.y : (j == 2) ? rv.z : rv.w;
                const int off = (j == 0) ? ov.x : (j == 1) ? ov.y : (j == 2) ? ov.z : ov.w;
                const float Rf = (float)R;
                const float gx = px*Rf, gy = py*Rf, gz = pz*Rf;
                int x0 = (int)floorf(gx); x0 = x0 < 0 ? 0 : (x0 > R-1 ? R-1 : x0);
                int y0 = (int)floorf(gy); y0 = y0 < 0 ? 0 : (y0 > R-1 ? R-1 : y0);
                int z0 = (int)floorf(gz); z0 = z0 < 0 ? 0 : (z0 > R-1 ? R-1 : z0);
                fx[j] = gx - (float)x0; fy[j] = gy - (float)y0; fz[j] = gz - (float)z0;
                const int s1 = R + 1, s2 = s1 * s1;
                const unsigned int* tab = tabu + off;
                const int b = x0 + y0*s1 + z0*s2;
                P[4*j+0] = *(const uint2a4*)(tab + b);
                P[4*j+1] = *(const uint2a4*)(tab + b + s1);
                P[4*j+2] = *(const uint2a4*)(tab + b + s2);
                P[4*j+3] = *(const uint2a4*)(tab + b + s1 + s2);
            }

            union { half8 v; h2 h[4]; } hv;
            #pragma unroll
            for (int j = 0; j < 4; ++j) {
                const _Float16 fxh = (_Float16)fx[j];
                const _Float16 fyh = (_Float16)fy[j];
                const _Float16 fzh = (_Float16)fz[j];
                const h2 fx2 = {fxh, fxh}, fy2 = {fyh, fyh}, fz2 = {fzh, fzh};
                const h2 c000 = as_h2(P[4*j+0].x), c100 = as_h2(P[4*j+0].y);
                const h2 c010 = as_h2(P[4*j+1].x), c110 = as_h2(P[4*j+1].y);
                const h2 c001 = as_h2(P[4*j+2].x), c101 = as_h2(P[4*j+2].y);
                const h2 c011 = as_h2(P[4*j+3].x), c111 = as_h2(P[4*j+3].y);
                const h2 a00 = c000 + fx2 * (c100 - c000);
                const h2 a10 = c010 + fx2 * (c110 - c010);
                const h2 a01 = c001 + fx2 * (c101 - c001);
                const h2 a11 = c011 + fx2 * (c111 - c011);
                const h2 b0  = a00 + fy2 * (a10 - a00);
                const h2 b1  = a01 + fy2 * (a11 - a01);
                hv.h[j] = b0 + fz2 * (b1 - b0);
            }
            *(half8*)&fls[(size_t)pl*40 + q*8] = hv.v;
        }
    }
    __syncthreads();

    // pick up S0 B-fragments before smM overwrites fls
    half8 B0s[4];
    #pragma unroll
    for (int nt = 0; nt < 4; ++nt)
        B0s[nt] = *(const half8*)&fls[(size_t)(w*64 + nt*16 + n)*40 + g*8];
    __syncthreads();

    auto storeQ = [&](int pt, int mt, floatx4 a) {   // relu + packed f16
        union { unsigned int u[2]; half4 v; } c;
        c.u[0] = pk_u32(fmaxf(a[0], 0.f), fmaxf(a[1], 0.f));
        c.u[1] = pk_u32(fmaxf(a[2], 0.f), fmaxf(a[3], 0.f));
        *(half4*)&smM[w][pt][16*mt + 4*g] = c.v;
    };

    // ===== S0: feats[32] @ ws0 -> H[64], relu
    {
        const half8 A0 = wfrag[0*64+lane], A1 = wfrag[1*64+lane];
        const half8 A2 = wfrag[2*64+lane], A3 = wfrag[3*64+lane];
        #pragma unroll
        for (int nt = 0; nt < 4; ++nt) {
            const int pt = nt*16 + n;
            const half8 B = B0s[nt];
            floatx4 a0 = MFMA16x16x32(A0, B, zz, 0,0,0);
            floatx4 a1 = MFMA16x16x32(A1, B, zz, 0,0,0);
            floatx4 a2 = MFMA16x16x32(A2, B, zz, 0,0,0);
            floatx4 a3 = MFMA16x16x32(A3, B, zz, 0,0,0);
            storeQ(pt, 0, a0); storeQ(pt, 1, a1); storeQ(pt, 2, a2); storeQ(pt, 3, a3);
        }
    }
    asm volatile("" ::: "memory");

    // ===== S1: H[64] @ ws1 -> G[16] (linear). sigma out; geo words in regs.
    unsigned int s1a[4], s1b[4];
    {
        const half8 A0 = wfrag[4*64+lane], A1 = wfrag[5*64+lane];
        #pragma unroll
        for (int nt = 0; nt < 4; ++nt) {
            const int pt = nt*16 + n;
            const half8 B0 = *(const half8*)&smM[w][pt][ 0 + 8*g];
            const half8 B1 = *(const half8*)&smM[w][pt][32 + 8*g];
            floatx4 acc = MFMA16x16x32(A0, B0, zz, 0,0,0);
            acc = MFMA16x16x32(A1, B1, acc, 0,0,0);
            s1a[nt] = pk_u32(acc[0], acc[1]);
            s1b[nt] = pk_u32(acc[2], acc[3]);
            if (g == 0) out[orig[nt]] = fabsf(acc[0]);   // sigma
        }
    }
    asm volatile("" ::: "memory");

    // ===== C0: hd'[32] @ wc0' -> c1[64], relu
    {
        const half8 A0 = wfrag[6*64+lane], A1 = wfrag[7*64+lane];
        const half8 A2 = wfrag[8*64+lane], A3 = wfrag[9*64+lane];
        const int srcA = ((g & 1) << 5) + n;
        #pragma unroll
        for (int nt = 0; nt < 4; ++nt) {
            const int pt = nt*16 + n;
            const unsigned int w0 = __shfl(s1a[nt], srcA);
            const unsigned int w1 = __shfl(s1b[nt], srcA);
            const unsigned int w2 = __shfl(s1a[nt], srcA + 16);
            const unsigned int w3 = __shfl(s1b[nt], srcA + 16);
            union { half8 v; unsigned int u[4]; } B;
            if (g < 2) {
                const float x = dX[nt], y = dY[nt], z = dZ[nt];
                const float xx = x*x, yy = y*y, zzq = z*z;
                const float xy = x*y, yz = y*z, xz = x*z;
                float s[8];
                if (g == 0) {
                    s[0] = 0.28209479177387814f;
                    s[1] = -0.48860251190291987f * y;
                    s[2] =  0.48860251190291987f * z;
                    s[3] = -0.48860251190291987f * x;
                    s[4] =  1.0925484305920792f * xy;
                    s[5] = -1.0925484305920792f * yz;
                    s[6] =  0.94617469575756f * zzq - 0.31539156525252005f;
                    s[7] = -1.0925484305920792f * xz;
                } else {
                    s[0] =  0.5462742152960396f * (xx - yy);
                    s[1] =  0.5900435899266435f * y * (yy - 3.0f*xx);
                    s[2] =  2.890611442640554f * xy * z;
                    s[3] =  0.4570457994644657f * y * (1.0f - 5.0f*zzq);
                    s[4] =  0.3731763325901154f * z * (5.0f*zzq - 3.0f);
                    s[5] =  0.4570457994644657f * x * (1.0f - 5.0f*zzq);
                    s[6] =  1.445305721320277f * z * (xx - yy);
                    s[7] =  0.5900435899266435f * x * (3.0f*yy - xx);
                }
                B.u[0] = pk_u32(s[0], s[1]); B.u[1] = pk_u32(s[2], s[3]);
                B.u[2] = pk_u32(s[4], s[5]); B.u[3] = pk_u32(s[6], s[7]);
            } else {
                B.u[0] = w0; B.u[1] = w1; B.u[2] = w2; B.u[3] = w3;
            }
            floatx4 a0 = MFMA16x16x32(A0, B.v, zz, 0,0,0);
            floatx4 a1 = MFMA16x16x32(A1, B.v, zz, 0,0,0);
            floatx4 a2 = MFMA16x16x32(A2, B.v, zz, 0,0,0);
            floatx4 a3 = MFMA16x16x32(A3, B.v, zz, 0,0,0);
            storeQ(pt, 0, a0); storeQ(pt, 1, a1); storeQ(pt, 2, a2); storeQ(pt, 3, a3);
        }
    }
    asm volatile("" ::: "memory");

    // ===== C1: c1[64] @ wc1 -> c2[64], relu
    {
        const half8 A0 = wfrag[10*64+lane], A1 = wfrag[11*64+lane];
        const half8 A2 = wfrag[12*64+lane], A3 = wfrag[13*64+lane];
        const half8 A4 = wfrag[14*64+lane], A5 = wfrag[15*64+lane];
        const half8 A6 = wfrag[16*64+lane], A7 = wfrag[17*64+lane];
        #pragma unroll
        for (int nt = 0; nt < 4; ++nt) {
            const int pt = nt*16 + n;
            const half8 B0 = *(const half8*)&smM[w][pt][ 0 + 8*g];
            const half8 B1 = *(const half8*)&smM[w][pt][32 + 8*g];
            floatx4 a0 = MFMA16x16x32(A0, B0, zz, 0,0,0); a0 = MFMA16x16x32(A1, B1, a0, 0,0,0);
            floatx4 a1 = MFMA16x16x32(A2, B0, zz, 0,0,0); a1 = MFMA16x16x32(A3, B1, a1, 0,0,0);
            floatx4 a2 = MFMA16x16x32(A4, B0, zz, 0,0,0); a2 = MFMA16x16x32(A5, B1, a2, 0,0,0);
            floatx4 a3 = MFMA16x16x32(A6, B0, zz, 0,0,0); a3 = MFMA16x16x32(A7, B1, a3, 0,0,0);
            storeQ(pt, 0, a0); storeQ(pt, 1, a1); storeQ(pt, 2, a2); storeQ(pt, 3, a3);
        }
    }
    asm volatile("" ::: "memory");

    // ===== C2: c2[64] @ wc2 -> color (|.|)
    {
        const half8 A0 = wfrag[18*64+lane], A1 = wfrag[19*64+lane];
        #pragma unroll
        for (int nt = 0; nt < 4; ++nt) {
            const int pt = nt*16 + n;
            const half8 B0 = *(const half8*)&smM[w][pt][ 0 + 8*g];
            const half8 B1 = *(const half8*)&smM[w][pt][32 + 8*g];
            floatx4 acc = MFMA16x16x32(A0, B0, zz, 0,0,0);
            acc = MFMA16x16x32(A1, B1, acc, 0,0,0);
            if (g == 0) out[NPTS + orig[nt]] = fabsf(acc[0]);
        }
    }
}

// ---------------------------------------------------------------------------
// Unsorted gather (tier-0 fallback, f16 tables, AoS feats in orig order).
// ---------------------------------------------------------------------------
__global__ __launch_bounds__(256, 4) void ngp_gather_lin(
    const float* __restrict__ xin, const unsigned int* __restrict__ tabu,
    _Float16* __restrict__ feats,
    int4 ra, int4 rb, int4 rc, int4 rd,
    int4 oa, int4 ob, int4 oc, int4 od)
{
    const int tid = blockIdx.x * 256 + threadIdx.x;
    const int p = tid >> 2;
    const int q = tid & 3;

    const float px = (xin[3*p+0] + 1.0f) * 0.5f;
    const float py = (xin[3*p+1] + 1.0f) * 0.5f;
    const float pz = (xin[3*p+2] + 1.0f) * 0.5f;

    const int4 rv = (q == 0) ? ra : (q == 1) ? rb : (q == 2) ? rc : rd;
    const int4 ov = (q == 0) ? oa : (q == 1) ? ob : (q == 2) ? oc : od;

    uint2a4 P[16];
    float fx[4], fy[4], fz[4];
    #pragma unroll
    for (int j = 0; j < 4; ++j) {
        const int R   = (j == 0) ? rv.x : (j == 1) ? rv.y : (j == 2) ? rv.z : rv.w;
        const int off = (j == 0) ? ov.x : (j == 1) ? ov.y : (j == 2) ? ov.z : ov.w;
        const float Rf = (float)R;
        const float gx = px*Rf, gy = py*Rf, gz = pz*Rf;
        int x0 = (int)floorf(gx); x0 = x0 < 0 ? 0 : (x0 > R-1 ? R-1 : x0);
        int y0 = (int)floorf(gy); y0 = y0 < 0 ? 0 : (y0 > R-1 ? R-1 : y0);
        int z0 = (int)floorf(gz); z0 = z0 < 0 ? 0 : (z0 > R-1 ? R-1 : z0);
        fx[j] = gx - (float)x0; fy[j] = gy - (float)y0; fz[j] = gz - (float)z0;
        const int s1 = R + 1, s2 = s1 * s1;
        const unsigned int* tab = tabu + off;
        const int b = x0 + y0*s1 + z0*s2;
        P[4*j+0] = *(const uint2a4*)(tab + b);
        P[4*j+1] = *(const uint2a4*)(tab + b + s1);
        P[4*j+2] = *(const uint2a4*)(tab + b + s2);
        P[4*j+3] = *(const uint2a4*)(tab + b + s1 + s2);
    }
    union { half8 v; h2 h[4]; } hv;
    #pragma unroll
    for (int j = 0; j < 4; ++j) {
        const _Float16 fxh = (_Float16)fx[j];
        const _Float16 fyh = (_Float16)fy[j];
        const _Float16 fzh = (_Float16)fz[j];
        const h2 fx2 = {fxh, fxh}, fy2 = {fyh, fyh}, fz2 = {fzh, fzh};
        const h2 c000 = as_h2(P[4*j+0].x), c100 = as_h2(P[4*j+0].y);
        const h2 c010 = as_h2(P[4*j+1].x), c110 = as_h2(P[4*j+1].y);
        const h2 c001 = as_h2(P[4*j+2].x), c101 = as_h2(P[4*j+2].y);
        const h2 c011 = as_h2(P[4*j+3].x), c111 = as_h2(P[4*j+3].y);
        const h2 a00 = c000 + fx2 * (c100 - c000);
        const h2 a10 = c010 + fx2 * (c110 - c010);
        const h2 a01 = c001 + fx2 * (c101 - c001);
        const h2 a11 = c011 + fx2 * (c111 - c011);
        const h2 b0  = a00 + fy2 * (a10 - a00);
        const h2 b1  = a01 + fy2 * (a11 - a01);
        hv.h[j] = b0 + fz2 * (b1 - b0);
    }
    *(half8*)&feats[(size_t)p*32 + q*8] = hv.v;
}

// ---------------------------------------------------------------------------
// Unsorted MLP (tier-0 fallback; round-12 MODE 0).
// ---------------------------------------------------------------------------
__global__ __launch_bounds__(256) void ngp_mlp_lin(
    const float* __restrict__ din, const _Float16* __restrict__ feats,
    const half8* __restrict__ wfrag, float* __restrict__ out)
{
    __shared__ __align__(16) _Float16 smM[4][64][72];

    const int tid  = threadIdx.x;
    const int w    = tid >> 6, lane = tid & 63;
    const int gbase = (blockIdx.x * 4 + w) * 64;

    const int n = lane & 15, g = lane >> 4;
    const floatx4 zz = {0.f, 0.f, 0.f, 0.f};

    unsigned int orig[4];
    float dX[4], dY[4], dZ[4];
    #pragma unroll
    for (int nt = 0; nt < 4; ++nt) {
        orig[nt] = gbase + nt*16 + n;
        dX[nt] = din[3*orig[nt]+0]; dY[nt] = din[3*orig[nt]+1]; dZ[nt] = din[3*orig[nt]+2];
    }

    auto storeQ = [&](int pt, int mt, floatx4 a) {
        union { unsigned int u[2]; half4 v; } c;
        c.u[0] = pk_u32(fmaxf(a[0], 0.f), fmaxf(a[1], 0.f));
        c.u[1] = pk_u32(fmaxf(a[2], 0.f), fmaxf(a[3], 0.f));
        *(half4*)&smM[w][pt][16*mt + 4*g] = c.v;
    };

    {
        const half8 A0 = wfrag[0*64+lane], A1 = wfrag[1*64+lane];
        const half8 A2 = wfrag[2*64+lane], A3 = wfrag[3*64+lane];
        #pragma unroll
        for (int nt = 0; nt < 4; ++nt) {
            const int pt = nt*16 + n;
            const half8 B = *(const half8*)&feats[(size_t)(gbase + pt)*32 + 8*g];
            floatx4 a0 = MFMA16x16x32(A0, B, zz, 0,0,0);
            floatx4 a1 = MFMA16x16x32(A1, B, zz, 0,0,0);
            floatx4 a2 = MFMA16x16x32(A2, B, zz, 0,0,0);
            floatx4 a3 = MFMA16x16x32(A3, B, zz, 0,0,0);
            storeQ(pt, 0, a0); storeQ(pt, 1, a1); storeQ(pt, 2, a2); storeQ(pt, 3, a3);
        }
    }
    asm volatile("" ::: "memory");

    unsigned int s1a[4], s1b[4];
    {
        const half8 A0 = wfrag[4*64+lane], A1 = wfrag[5*64+lane];
        #pragma unroll
        for (int nt = 0; nt < 4; ++nt) {
            const int pt = nt*16 + n;
            const half8 B0 = *(const half8*)&smM[w][pt][ 0 + 8*g];
            const half8 B1 = *(const half8*)&smM[w][pt][32 + 8*g];
            floatx4 acc = MFMA16x16x32(A0, B0, zz, 0,0,0);
            acc = MFMA16x16x32(A1, B1, acc, 0,0,0);
            s1a[nt] = pk_u32(acc[0], acc[1]);
            s1b[nt] = pk_u32(acc[2], acc[3]);
            if (g == 0) out[orig[nt]] = fabsf(acc[0]);
        }
    }
    asm volatile("" ::: "memory");

    {
        const half8 A0 = wfrag[6*64+lane], A1 = wfrag[7*64+lane];
        const half8 A2 = wfrag[8*64+lane], A3 = wfrag[9*64+lane];
        const int srcA = ((g & 1) << 5) + n;
        #pragma unroll
        for (int nt = 0; nt < 4; ++nt) {
            const int pt = nt*16 + n;
            const unsigned int w0 = __shfl(s1a[nt], srcA);
            const unsigned int w1 = __shfl(s1b[nt], srcA);
            const unsigned int w2 = __shfl(s1a[nt], srcA + 16);
            const unsigned int w3 = __shfl(s1b[nt], srcA + 16);
            union { half8 v; unsigned int u[4]; } B;
            if (g < 2) {
                const float x = dX[nt], y = dY[nt], z = dZ[nt];
                const float xx = x*x, yy = y*y, zzq = z*z;
                const float xy = x*y, yz = y*z, xz = x*z;
                float s[8];
                if (g == 0) {
                    s[0] = 0.28209479177387814f;
                    s[1] = -0.48860251190291987f * y;
                    s[2] =  0.48860251190291987f * z;
                    s[3] = -0.48860251190291987f * x;
                    s[4] =  1.0925484305920792f * xy;
                    s[5] = -1.0925484305920792f * yz;
                    s[6] =  0.94617469575756f * zzq - 0.31539156525252005f;
                    s[7] = -1.0925484305920792f * xz;
                } else {
                    s[0] =  0.5462742152960396f * (xx - yy);
                    s[1] =  0.5900435899266435f * y * (yy - 3.0f*xx);
                    s[2] =  2.890611442640554f * xy * z;
                    s[3] =  0.4570457994644657f * y * (1.0f - 5.0f*zzq);
                    s[4] =  0.3731763325901154f * z * (5.0f*zzq - 3.0f);
                    s[5] =  0.4570457994644657f * x * (1.0f - 5.0f*zzq);
                    s[6] =  1.445305721320277f * z * (xx - yy);
                    s[7] =  0.5900435899266435f * x * (3.0f*yy - xx);
                }
                B.u[0] = pk_u32(s[0], s[1]); B.u[1] = pk_u32(s[2], s[3]);
                B.u[2] = pk_u32(s[4], s[5]); B.u[3] = pk_u32(s[6], s[7]);
            } else {
                B.u[0] = w0; B.u[1] = w1; B.u[2] = w2; B.u[3] = w3;
            }
            floatx4 a0 = MFMA16x16x32(A0, B.v, zz, 0,0,0);
            floatx4 a1 = MFMA16x16x32(A1, B.v, zz, 0,0,0);
            floatx4 a2 = MFMA16x16x32(A2, B.v, zz, 0,0,0);
            floatx4 a3 = MFMA16x16x32(A3, B.v, zz, 0,0,0);
            storeQ(pt, 0, a0); storeQ(pt, 1, a1); storeQ(pt, 2, a2); storeQ(pt, 3, a3);
        }
    }
    asm volatile("" ::: "memory");

    {
        const half8 A0 = wfrag[10*64+lane], A1 = wfrag[11*64+lane];
        const half8 A2 = wfrag[12*64+lane], A3 = wfrag[13*64+lane];
        const half8 A4 = wfrag[14*64+lane], A5 = wfrag[15*64+lane];
        const half8 A6 = wfrag[16*64+lane], A7 = wfrag[17*64+lane];
        #pragma unroll
        for (int nt = 0; nt < 4; ++nt) {
            const int pt = nt*16 + n;
            const half8 B0 = *(const half8*)&smM[w][pt][ 0 + 8*g];
            const half8 B1 = *(const half8*)&smM[w][pt][32 + 8*g];
            floatx4 a0 = MFMA16x16x32(A0, B0, zz, 0,0,0); a0 = MFMA16x16x32(A1, B1, a0, 0,0,0);
            floatx4 a1 = MFMA16x16x32(A2, B0, zz, 0,0,0); a1 = MFMA16x16x32(A3, B1, a1, 0,0,0);
            floatx4 a2 = MFMA16x16x32(A4, B0, zz, 0,0,0); a2 = MFMA16x16x32(A5, B1, a2, 0,0,0);
            floatx4 a3 = MFMA16x16x32(A6, B0, zz, 0,0,0); a3 = MFMA16x16x32(A7, B1, a3, 0,0,0);
            storeQ(pt, 0, a0); storeQ(pt, 1, a1); storeQ(pt, 2, a2); storeQ(pt, 3, a3);
        }
    }
    asm volatile("" ::: "memory");

    {
        const half8 A0 = wfrag[18*64+lane], A1 = wfrag[19*64+lane];
        #pragma unroll
        for (int nt = 0; nt < 4; ++nt) {
            const int pt = nt*16 + n;
            const half8 B0 = *(const half8*)&smM[w][pt][ 0 + 8*g];
            const half8 B1 = *(const half8*)&smM[w][pt][32 + 8*g];
            floatx4 acc = MFMA16x16x32(A0, B0, zz, 0,0,0);
            acc = MFMA16x16x32(A1, B1, acc, 0,0,0);
            if (g == 0) out[NPTS + orig[nt]] = fabsf(acc[0]);
        }
    }
}

extern "C" void kernel_launch(void* const* d_in, const int* in_sizes, int n_in,
                              void* d_out, int out_size, void* d_ws, size_t ws_size,
                              hipStream_t stream)
{
    const float* x   = (const float*)d_in[0];
    const float* d   = (const float*)d_in[1];
    const float* emb = (const float*)d_in[2];
    const float* ws0 = (const float*)d_in[3];
    const float* ws1 = (const float*)d_in[4];
    const float* wc0 = (const float*)d_in[5];
    const float* wc1 = (const float*)d_in[6];
    const float* wc2 = (const float*)d_in[7];
    float* out = (float*)d_out;

    // tier-1 (fused) layout: wfrag | tabu | rnk | hist | boff | pd
    const size_t OFF_WFRAG = 0;
    const size_t OFF_TABU  = 32768;
    const size_t OFF_RNK   = OFF_TABU + 8388608;           // 4 MB
    const size_t OFF_HIST  = OFF_RNK + 4194304;            // 128 KB
    const size_t OFF_BOFF  = OFF_HIST + NBUCK*4;           // 128 KB
    const size_t OFF_PD    = OFF_BOFF + NBUCK*4;           // 32 MB
    const size_t NEED_SORT = OFF_PD + (size_t)NPTS*32;
    // tier-0 (lin) layout: wfrag | tabu | feats
    const size_t OFF_FEATS = OFF_RNK;
    const size_t NEED_LIN  = OFF_FEATS + (size_t)NPTS*64;

    half8* wfrag        = (half8*)((char*)d_ws + OFF_WFRAG);
    unsigned int* tabu  = (unsigned int*)((char*)d_ws + OFF_TABU);
    unsigned int* rnk   = (unsigned int*)((char*)d_ws + OFF_RNK);
    unsigned int* hist  = (unsigned int*)((char*)d_ws + OFF_HIST);
    unsigned int* boff  = (unsigned int*)((char*)d_ws + OFF_BOFF);
    float4* pd          = (float4*)((char*)d_ws + OFF_PD);
    _Float16* feats     = (_Float16*)((char*)d_ws + OFF_FEATS);

    // Replicate numpy's host-side RESOLUTIONS computation bit-for-bit.
    int r[16], off[16];
    const double s = std::exp(std::log(4.0) / 15.0);
    int acc = 0;
    for (int l = 0; l < 16; ++l) {
        r[l] = (int)std::floor(16.0 * std::pow(s, (double)l));
        off[l] = acc;
        acc += (r[l]+1)*(r[l]+1)*(r[l]+1);
    }
    const int4 ra = {r[0],  r[1],  r[2],  r[3]};
    const int4 rb = {r[4],  r[5],  r[6],  r[7]};
    const int4 rc = {r[8],  r[9],  r[10], r[11]};
    const int4 rd = {r[12], r[13], r[14], r[15]};
    const int4 oa = {off[0],  off[1],  off[2],  off[3]};
    const int4 ob = {off[4],  off[5],  off[6],  off[7]};
    const int4 oc = {off[8],  off[9],  off[10], off[11]};
    const int4 od = {off[12], off[13], off[14], off[15]};

    prepack_weights<<<20, 64, 0, stream>>>(ws0, ws1, wc0, wc1, wc2, wfrag);

    const int nmax = (r[15]+1)*(r[15]+1)*(r[15]+1);
    dim3 cgrid((nmax + 255) / 256, 17);   // y==16: hist zero

    if (ws_size >= NEED_SORT) {
        convert_tables<<<cgrid, 256, 0, stream>>>(emb, tabu, hist, 1, ra, rb, rc, rd, oa, ob, oc, od);
        hist_kernel<<<NPTS/256, 256, 0, stream>>>(x, hist, rnk);
        scan_kernel<<<1, 1024, 0, stream>>>(hist, boff);
        scatter_pd<<<NPTS/256, 256, 0, stream>>>(x, d, boff, rnk, pd);
        ngp_fused_sorted<<<NPTS/256, 256, 0, stream>>>(pd, tabu, wfrag, out, ra, rb, rc, rd, oa, ob, oc, od);
    } else if (ws_size >= NEED_LIN) {
        convert_tables<<<cgrid, 256, 0, stream>>>(emb, tabu, hist, 0, ra, rb, rc, rd, oa, ob, oc, od);
        ngp_gather_lin<<<NPTS*4/256, 256, 0, stream>>>(x, tabu, feats, ra, rb, rc, rd, oa, ob, oc, od);
        ngp_mlp_lin<<<NPTS/256, 256, 0, stream>>>(d, feats, wfrag, out);
    }
}